// Round 8
// baseline (154.371 us; speedup 1.0000x reference)
//
#include <hip/hip_runtime.h>
#include <hip/hip_bf16.h>

#define BB 8
#define TT 2048
#define CC 1024
#define HH 64
#define NSPLIT 8

typedef __attribute__((ext_vector_type(8)))  short bf16x8;
typedef __attribute__((ext_vector_type(4)))  float f32x4;
typedef __attribute__((ext_vector_type(16))) float f32x16;
typedef __attribute__((ext_vector_type(8)))  unsigned short us8;
typedef unsigned int u32;

static __device__ __forceinline__ unsigned short f2bf(float f) {
    union { float f; unsigned int u; } v; v.f = f;
    unsigned int u = v.u;
    return (unsigned short)((u + 0x7FFFu + ((u >> 16) & 1u)) >> 16);  // RNE
}
static __device__ __forceinline__ float bf2f(unsigned short s) {
    union { u32 u; float f; } v; v.u = ((u32)s) << 16; return v.f;
}
static __device__ __forceinline__ u32 fbits(float f) {
    union { float f; u32 u; } v; v.f = f; return v.u;
}

// ---------------------------------------------------------------------------
// Kernel 0: W [C][H] fp32 -> Wt [3][H][C] bf16 (transposed), fold log2(e)/8
// into Wq so QK^T scores come out in the log2 domain. (unchanged)
// ---------------------------------------------------------------------------
__global__ __launch_bounds__(256) void prep_weights(
        const float* __restrict__ Wq, const float* __restrict__ Wk,
        const float* __restrict__ Wv, unsigned short* __restrict__ Wt) {
    __shared__ float tile[64][65];
    int w  = blockIdx.x >> 4;       // 0..2
    int c0 = (blockIdx.x & 15) * 64;
    const float* W = (w == 0) ? Wq : (w == 1) ? Wk : Wv;
    int li = threadIdx.x;
    {
        int c = li >> 2, h4 = (li & 3) * 16;
        const float* src = W + (size_t)(c0 + c) * HH + h4;
        #pragma unroll
        for (int i = 0; i < 4; ++i) {
            float4 v4 = *(const float4*)(src + i * 4);
            tile[c][h4 + i*4 + 0] = v4.x; tile[c][h4 + i*4 + 1] = v4.y;
            tile[c][h4 + i*4 + 2] = v4.z; tile[c][h4 + i*4 + 3] = v4.w;
        }
    }
    __syncthreads();
    float scale = (w == 0) ? 0.1803368802f : 1.0f;   // log2(e)/sqrt(64)
    int h = li >> 2, cg = (li & 3) * 16;
    unsigned short* dst = Wt + (size_t)w * HH * CC + (size_t)h * CC + c0 + cg;
    #pragma unroll
    for (int i = 0; i < 16; ++i) dst[i] = f2bf(tile[cg + i][h] * scale);
}

// ---------------------------------------------------------------------------
// Kernel 1: fused QKV projection, v5. ROUND-8 CHANGE (the only one):
// X never touches LDS. Each wave loads its A-fragment rows DIRECTLY from
// global x (A[m=lane&15][k=quad*8+j] -> 8 contiguous fp32 = 2 float4 per
// ks), reg-prefetched one full K-iteration ahead, packed fp32->bf16 with
// v_perm truncation (4 perms per 8 values; the ~0.2% systematic p-shift
// cancels in softmax's ratio). The 4 ng-waves read duplicate lines
// near-simultaneously -> L1/L2 absorb; HBM stays ~64 MB. LDS now carries
// only W (gll dbuf, unchanged) -> X's cvt+ds_write+barrier round-trip and
// half the per-iter LDS traffic are gone. W pipeline, MFMA tiling, and
// epilogue are round-7 verbatim (epilogue Vl scratch moved into Ws).
// ---------------------------------------------------------------------------
__global__ __launch_bounds__(512, 4) void proj_qkv(
        const float* __restrict__ x, const unsigned short* __restrict__ Wt,
        unsigned short* __restrict__ qws, unsigned short* __restrict__ kws,
        unsigned short* __restrict__ vws) {
    __shared__ unsigned short Ws[2][192 * 64];   // 24 KB each
    int tid = threadIdx.x;
    int wv = tid >> 6, lane = tid & 63;
    int quad = (lane >> 4) & 3, lq = lane & 15;
    int mg = wv >> 2, ng = wv & 3;
    int r0 = blockIdx.x * 32;

    // direct A source: row r0 + mg*16 + lq, cols quad*8 + [0..7] within chunk
    const float* asrc = x + (size_t)(r0 + mg * 16 + lq) * CC + quad * 8;
    float4 an[4];   // prefetched next-iter A: [ks*2 + half]

    f32x4 acc[3];
    #pragma unroll
    for (int nt = 0; nt < 3; ++nt)
        #pragma unroll
        for (int i = 0; i < 4; ++i) acc[nt][i] = 0.0f;

    auto stageW = [&](int buf, int kc) {
        #pragma unroll
        for (int i = 0; i < 3; ++i) {
            int fp = tid + i * 512;            // 0..1535
            int r = fp >> 3, pb = fp & 7, g = pb ^ (r & 7);
            const u32 __attribute__((address_space(1)))* gsrc =
                (const u32 __attribute__((address_space(1)))*)
                    (Wt + (size_t)r * CC + kc * 64 + g * 8);
            u32 __attribute__((address_space(3)))* ldst =
                (u32 __attribute__((address_space(3)))*)(&Ws[buf][fp * 8]);
            __builtin_amdgcn_global_load_lds(gsrc, ldst, 16, 0, 0);
        }
    };
    auto loadA = [&](int kc) {
        #pragma unroll
        for (int ks = 0; ks < 2; ++ks) {
            an[ks * 2 + 0] = *(const float4*)(asrc + kc * 64 + ks * 32);
            an[ks * 2 + 1] = *(const float4*)(asrc + kc * 64 + ks * 32 + 4);
        }
    };
    // pack 8 fp32 (two float4) -> bf16x8 by truncation (4 v_perm)
    auto pack8 = [&](const float4& a, const float4& b) -> bf16x8 {
        u32 w[4];
        w[0] = __builtin_amdgcn_perm(fbits(a.y), fbits(a.x), 0x07060302u);
        w[1] = __builtin_amdgcn_perm(fbits(a.w), fbits(a.z), 0x07060302u);
        w[2] = __builtin_amdgcn_perm(fbits(b.y), fbits(b.x), 0x07060302u);
        w[3] = __builtin_amdgcn_perm(fbits(b.w), fbits(b.z), 0x07060302u);
        union { u32 u[4]; bf16x8 v; } r;
        r.u[0] = w[0]; r.u[1] = w[1]; r.u[2] = w[2]; r.u[3] = w[3];
        return r.v;
    };

    // prologue
    loadA(0);
    stageW(0, 0);

    for (int kc = 0; kc < 16; ++kc) {
        int cur = kc & 1;
        __syncthreads();                     // Ws[cur] ready; Ws[1-cur] free
        if (kc < 15) stageW(1 - cur, kc + 1);
        float4 ac[4];
        #pragma unroll
        for (int i = 0; i < 4; ++i) ac[i] = an[i];
        if (kc < 15) loadA(kc + 1);          // issue next-iter A loads now
        #pragma unroll
        for (int ks = 0; ks < 2; ++ks) {
            int g = ks * 4 + quad;
            bf16x8 a = pack8(ac[ks * 2], ac[ks * 2 + 1]);
            bf16x8 b[3];
            #pragma unroll
            for (int nt = 0; nt < 3; ++nt) {
                int brow = ng * 48 + nt * 16 + lq;
                b[nt] = *(const bf16x8*)&Ws[cur][brow * 64 + (g ^ (lq & 7)) * 8];
            }
            #pragma unroll
            for (int nt = 0; nt < 3; ++nt)
                acc[nt] = __builtin_amdgcn_mfma_f32_16x16x32_bf16(
                    a, b[nt], acc[nt], 0, 0, 0);
        }
    }

    // epilogue: q,k direct; v via LDS transpose (scratch in Ws, done with it)
    __syncthreads();
    unsigned short* Vl = (unsigned short*)Ws;   // [h][row], pitch 36 (4.6 KB)
    #pragma unroll
    for (int nt = 0; nt < 3; ++nt) {
        int g = ng * 48 + nt * 16 + lq;
        #pragma unroll
        for (int i = 0; i < 4; ++i) {
            int row = mg * 16 + quad * 4 + i;
            unsigned short bv = f2bf(acc[nt][i]);
            if (g < 64)       qws[(size_t)(r0 + row) * HH + g] = bv;
            else if (g < 128) kws[(size_t)(r0 + row) * HH + (g - 64)] = bv;
            else              Vl[(g - 128) * 36 + row] = bv;
        }
    }
    __syncthreads();
    if (tid < 256) {
        int h = tid >> 2, tb = (tid & 3) * 8;
        int b = r0 >> 11, rr = r0 & (TT - 1);
        *(us8*)(vws + ((size_t)b * HH + h) * TT + rr + tb) =
            *(const us8*)&Vl[h * 36 + tb];
    }
}

// ---------------------------------------------------------------------------
// Kernel 2: causal attention — round-7 PASSED version, verbatim.
// ---------------------------------------------------------------------------
__global__ __launch_bounds__(128, 3) void attn(
        const unsigned short* __restrict__ qws,
        const unsigned short* __restrict__ kws,
        const unsigned short* __restrict__ vws,
        unsigned short* __restrict__ Op, float* __restrict__ Lp) {
    __shared__ unsigned short Kt[32][72];   // [key][h]
    __shared__ unsigned short Vt[64][40];   // [h][key]
    __shared__ unsigned short Ps[64][40];   // [q][key], rows wave-private
    int ti = blockIdx.x;            // 64-row q tile, 0..31
    int s  = blockIdx.y;            // kv split 0..NSPLIT-1
    int b  = blockIdx.z;
    int last = 2 * ti + 1;          // last 32-key chunk index for this tile
    if (s > last) return;
    int tid = threadIdx.x, wv = tid >> 6, lane = tid & 63;
    int half = lane >> 5, l31 = lane & 31;

    bf16x8 qf[4];
    {
        const unsigned short* qp =
            qws + ((size_t)b * TT + ti * 64 + wv * 32 + l31) * HH + half * 8;
        #pragma unroll
        for (int ks = 0; ks < 4; ++ks) qf[ks] = *(const bf16x8*)(qp + ks * 16);
    }
    f32x16 O0, O1, Lc;
    #pragma unroll
    for (int i = 0; i < 16; ++i) { O0[i] = 0.f; O1[i] = 0.f; Lc[i] = 0.f; }
    bf16x8 ones;
    #pragma unroll
    for (int i = 0; i < 8; ++i) ones[i] = (short)0x3F80;

    for (int jc = s; jc <= last; jc += NSPLIT) {
        __syncthreads();   // prior iter's K/V reads done before restage
        #pragma unroll
        for (int i = 0; i < 2; ++i) {   // K: 32 keys x 64 h
            int slot = tid + i * 128;
            int r = slot >> 3, g = slot & 7;
            *(us8*)&Kt[r][g * 8] =
                *(const us8*)(kws + ((size_t)b * TT + jc * 32 + r) * HH + g * 8);
        }
        #pragma unroll
        for (int i = 0; i < 2; ++i) {   // V: 64 h x 32 keys
            int slot = tid + i * 128;
            int h = slot >> 2, kb = slot & 3;
            *(us8*)&Vt[h][kb * 8] =
                *(const us8*)(vws + ((size_t)b * HH + h) * TT + jc * 32 + kb * 8);
        }
        __syncthreads();
        f32x16 S;
        #pragma unroll
        for (int i = 0; i < 16; ++i) S[i] = 0.f;
        #pragma unroll
        for (int ks = 0; ks < 4; ++ks) {
            bf16x8 kf = *(const bf16x8*)&Kt[l31][ks * 16 + half * 8];
            S = __builtin_amdgcn_mfma_f32_32x32x16_bf16(qf[ks], kf, S, 0, 0, 0);
        }
        bool diag = (jc >= 2 * ti + wv);   // chunk can touch this wave's diagonal
        #pragma unroll
        for (int r = 0; r < 16; ++r) {
            int pat = (r & 3) + 8 * (r >> 2) + 4 * half;    // local q row in wave
            float p = __builtin_amdgcn_exp2f(S[r]);
            if (diag && jc * 32 + l31 > ti * 64 + wv * 32 + pat) p = 0.0f;
            Ps[wv * 32 + pat][l31] = f2bf(p);
        }
        // no __syncthreads: each wave reads only its own 32 Ps rows
        #pragma unroll
        for (int ks = 0; ks < 2; ++ks) {
            bf16x8 pa  = *(const bf16x8*)&Ps[wv * 32 + l31][ks * 16 + half * 8];
            bf16x8 vf0 = *(const bf16x8*)&Vt[l31][ks * 16 + half * 8];
            bf16x8 vf1 = *(const bf16x8*)&Vt[32 + l31][ks * 16 + half * 8];
            O0 = __builtin_amdgcn_mfma_f32_32x32x16_bf16(pa, vf0, O0, 0, 0, 0);
            O1 = __builtin_amdgcn_mfma_f32_32x32x16_bf16(pa, vf1, O1, 0, 0, 0);
            Lc = __builtin_amdgcn_mfma_f32_32x32x16_bf16(pa, ones, Lc, 0, 0, 0);
        }
    }
    // deterministic per-split partial store (bf16)
    unsigned short* Ob =
        Op + (((size_t)s * BB + b) * TT + ti * 64 + wv * 32) * HH;
    #pragma unroll
    for (int r = 0; r < 16; ++r) {
        int pat = (r & 3) + 8 * (r >> 2) + 4 * half;
        Ob[(size_t)pat * HH + l31]      = f2bf(O0[r]);
        Ob[(size_t)pat * HH + 32 + l31] = f2bf(O1[r]);
    }
    if (l31 == 0) {
        #pragma unroll
        for (int r = 0; r < 16; ++r) {
            int pat = (r & 3) + 8 * (r >> 2) + 4 * half;
            Lp[((size_t)s * BB + b) * TT + ti * 64 + wv * 32 + pat] = Lc[r];
        }
    }
}

// ---------------------------------------------------------------------------
// Kernel 3: out = (sum_s Op[s]) / (sum_s Lp[s]) — round-7 PASSED version.
// 65536 threads = 256 blocks (4 threads/row).
// ---------------------------------------------------------------------------
__global__ __launch_bounds__(256) void norm_out(
        const unsigned short* __restrict__ Op, const float* __restrict__ Lp,
        float* __restrict__ out) {
    int idx = blockIdx.x * 256 + threadIdx.x;     // 65536 total
    int g = idx >> 2;                             // global row b*T + t, <16384
    int hseg = (idx & 3) * 16;
    int ti = (g & (TT - 1)) >> 6;
    int ns = min(2 * ti + 2, NSPLIT);
    float a[16];
    #pragma unroll
    for (int j = 0; j < 16; ++j) a[j] = 0.f;
    float Ls = 0.f;
    for (int s = 0; s < ns; ++s) {
        const unsigned short* base =
            Op + ((size_t)s * BB * TT + g) * HH + hseg;
        us8 u0 = *(const us8*)base;
        us8 u1 = *(const us8*)(base + 8);
        #pragma unroll
        for (int j = 0; j < 8; ++j) { a[j] += bf2f(u0[j]); a[8 + j] += bf2f(u1[j]); }
        Ls += Lp[(size_t)s * BB * TT + g];
    }
    float inv = 1.0f / Ls;
    float* ob = out + (size_t)g * HH + hseg;
    #pragma unroll
    for (int q = 0; q < 4; ++q) {
        float4 v = make_float4(a[q*4] * inv, a[q*4+1] * inv,
                               a[q*4+2] * inv, a[q*4+3] * inv);
        ((float4*)ob)[q] = v;
    }
}

// ---------------------------------------------------------------------------
extern "C" void kernel_launch(void* const* d_in, const int* in_sizes, int n_in,
                              void* d_out, int out_size, void* d_ws, size_t ws_size,
                              hipStream_t stream) {
    (void)in_sizes; (void)n_in; (void)out_size; (void)ws_size;
    const float* x  = (const float*)d_in[0];
    const float* Wq = (const float*)d_in[1];
    const float* Wk = (const float*)d_in[2];
    const float* Wv = (const float*)d_in[3];
    float* out = (float*)d_out;

    char* ws = (char*)d_ws;
    unsigned short* Wt  = (unsigned short*)ws;                          // 384 KB
    unsigned short* qws = (unsigned short*)(ws + (1u << 19));           // 2 MB
    unsigned short* kws = (unsigned short*)(ws + (1u << 19) + (1u << 21));
    unsigned short* vws = (unsigned short*)(ws + (1u << 19) + (2u << 21));
    unsigned short* Op  = (unsigned short*)(ws + (1u << 19) + (3u << 21)); // 16 MB bf16
    float*          Lp  = (float*)(ws + (1u << 19) + (3u << 21) + (1u << 24)); // 512 KB

    prep_weights<<<48, 256, 0, stream>>>(Wq, Wk, Wv, Wt);
    proj_qkv<<<512, 512, 0, stream>>>(x, Wt, qws, kws, vws);
    attn<<<dim3(32, NSPLIT, 8), 128, 0, stream>>>(qws, kws, vws, Op, Lp);
    norm_out<<<256, 256, 0, stream>>>(Op, Lp, out);
}

// Round 9
// 136.903 us; speedup vs baseline: 1.1276x; 1.1276x over previous
//
#include <hip/hip_runtime.h>
#include <hip/hip_bf16.h>

#define BB 8
#define TT 2048
#define CC 1024
#define HH 64
#define NSPLIT 8

typedef __attribute__((ext_vector_type(8)))  short bf16x8;
typedef __attribute__((ext_vector_type(4)))  float f32x4;
typedef __attribute__((ext_vector_type(16))) float f32x16;
typedef __attribute__((ext_vector_type(8)))  unsigned short us8;
typedef unsigned int u32;

static __device__ __forceinline__ unsigned short f2bf(float f) {
    union { float f; unsigned int u; } v; v.f = f;
    unsigned int u = v.u;
    return (unsigned short)((u + 0x7FFFu + ((u >> 16) & 1u)) >> 16);  // RNE
}
static __device__ __forceinline__ float bf2f(unsigned short s) {
    union { u32 u; float f; } v; v.u = ((u32)s) << 16; return v.f;
}

// ---------------------------------------------------------------------------
// Kernel 0: W [C][H] fp32 -> Wt [3][H][C] bf16 (transposed), fold log2(e)/8
// into Wq so QK^T scores come out in the log2 domain. (unchanged)
// ---------------------------------------------------------------------------
__global__ __launch_bounds__(256) void prep_weights(
        const float* __restrict__ Wq, const float* __restrict__ Wk,
        const float* __restrict__ Wv, unsigned short* __restrict__ Wt) {
    __shared__ float tile[64][65];
    int w  = blockIdx.x >> 4;       // 0..2
    int c0 = (blockIdx.x & 15) * 64;
    const float* W = (w == 0) ? Wq : (w == 1) ? Wk : Wv;
    int li = threadIdx.x;
    {
        int c = li >> 2, h4 = (li & 3) * 16;
        const float* src = W + (size_t)(c0 + c) * HH + h4;
        #pragma unroll
        for (int i = 0; i < 4; ++i) {
            float4 v4 = *(const float4*)(src + i * 4);
            tile[c][h4 + i*4 + 0] = v4.x; tile[c][h4 + i*4 + 1] = v4.y;
            tile[c][h4 + i*4 + 2] = v4.z; tile[c][h4 + i*4 + 3] = v4.w;
        }
    }
    __syncthreads();
    float scale = (w == 0) ? 0.1803368802f : 1.0f;   // log2(e)/sqrt(64)
    int h = li >> 2, cg = (li & 3) * 16;
    unsigned short* dst = Wt + (size_t)w * HH * CC + (size_t)h * CC + c0 + cg;
    #pragma unroll
    for (int i = 0; i < 16; ++i) dst[i] = f2bf(tile[cg + i][h] * scale);
}

// ---------------------------------------------------------------------------
// Kernel 1: fused QKV projection, v6. ROUND-9 CHANGE: cut L2/L3 fabric bytes
// (round-8 showed fabric, not waves, is binding). M=64 tiles x K-split 2:
// grid (256 m, 2 kh). W restage traffic: 512 x 384KB = 197MB -> 512 x 192KB
// = 98MB; x still read exactly once; 2x MFMA per barrier (12/wave/iter)
// amortizes each drain. Pipeline (gll W dbuf + 2-deep X reg prefetch) is
// round-7 verbatim. Output: bf16 partials Pp[kh][row][192] (q|k|v cols);
// halves summed + v transposed in qkv_reduce.
// ---------------------------------------------------------------------------
__global__ __launch_bounds__(512, 4) void proj_qkv(
        const float* __restrict__ x, const unsigned short* __restrict__ Wt,
        unsigned short* __restrict__ Pp) {
    __shared__ unsigned short Xs[2][64 * 64];    // 8 KB each
    __shared__ unsigned short Ws[2][192 * 64];   // 24 KB each
    int tid = threadIdx.x;
    int wv = tid >> 6, lane = tid & 63;
    int quad = (lane >> 4) & 3, lq = lane & 15;
    int mg = wv >> 2, ng = wv & 3;
    int r0 = blockIdx.x * 64;
    int k0 = blockIdx.y * 512;     // K-half base

    // X staging: all 512 threads, 8 consecutive fp32 each (64 rows x 64 cols)
    int xr = tid >> 3, xg = tid & 7;
    const float* xsrc = x + (size_t)(r0 + xr) * CC + k0 + xg * 8;
    int xdst = xr * 64 + ((xg ^ (xr & 7)) * 8);
    float4 xa[2], xb[2];                         // 2-deep prefetch sets

    f32x4 acc[2][3];
    #pragma unroll
    for (int mt = 0; mt < 2; ++mt)
        #pragma unroll
        for (int nt = 0; nt < 3; ++nt)
            #pragma unroll
            for (int i = 0; i < 4; ++i) acc[mt][nt][i] = 0.0f;

    auto stageW = [&](int buf, int kc) {
        #pragma unroll
        for (int i = 0; i < 3; ++i) {
            int fp = tid + i * 512;            // 0..1535
            int r = fp >> 3, pb = fp & 7, g = pb ^ (r & 7);
            const u32 __attribute__((address_space(1)))* gsrc =
                (const u32 __attribute__((address_space(1)))*)
                    (Wt + (size_t)r * CC + k0 + kc * 64 + g * 8);
            u32 __attribute__((address_space(3)))* ldst =
                (u32 __attribute__((address_space(3)))*)(&Ws[buf][fp * 8]);
            __builtin_amdgcn_global_load_lds(gsrc, ldst, 16, 0, 0);
        }
    };
    auto loadX = [&](int set, int kc) {
        xa[set] = *(const float4*)(xsrc + kc * 64);
        xb[set] = *(const float4*)(xsrc + kc * 64 + 4);
    };
    auto writeX = [&](int set, int buf) {
        unsigned short h[8];
        h[0]=f2bf(xa[set].x); h[1]=f2bf(xa[set].y);
        h[2]=f2bf(xa[set].z); h[3]=f2bf(xa[set].w);
        h[4]=f2bf(xb[set].x); h[5]=f2bf(xb[set].y);
        h[6]=f2bf(xb[set].z); h[7]=f2bf(xb[set].w);
        *(us8*)&Xs[buf][xdst] = *(const us8*)h;
    };

    // prologue: X[0] -> buf0 now; X[1] held in regs for iter 0's stage phase
    loadX(0, 0); loadX(1, 1);
    stageW(0, 0);
    writeX(0, 0);

    for (int kc = 0; kc < 8; ++kc) {
        int cur = kc & 1;
        __syncthreads();                     // buf[cur] ready; buf[1-cur] free
        if (kc < 7) stageW(1 - cur, kc + 1);
        if (kc < 6) loadX(kc & 1, kc + 2);   // refill freed set
        #pragma unroll
        for (int ks = 0; ks < 2; ++ks) {
            int g = ks * 4 + quad;
            bf16x8 a[2], b[3];
            #pragma unroll
            for (int mt = 0; mt < 2; ++mt) {
                int arow = mg * 32 + mt * 16 + lq;
                a[mt] = *(const bf16x8*)&Xs[cur][arow * 64 + (g ^ (lq & 7)) * 8];
            }
            #pragma unroll
            for (int nt = 0; nt < 3; ++nt) {
                int brow = ng * 48 + nt * 16 + lq;
                b[nt] = *(const bf16x8*)&Ws[cur][brow * 64 + (g ^ (lq & 7)) * 8];
            }
            #pragma unroll
            for (int mt = 0; mt < 2; ++mt)
                #pragma unroll
                for (int nt = 0; nt < 3; ++nt)
                    acc[mt][nt] = __builtin_amdgcn_mfma_f32_16x16x32_bf16(
                        a[mt], b[nt], acc[mt][nt], 0, 0, 0);
        }
        if (kc < 7) writeX((kc + 1) & 1, 1 - cur);  // X[kc+1]
    }

    // epilogue: straight bf16 partial store, cols 0..191 = q|k|v
    unsigned short* Pb =
        Pp + ((size_t)blockIdx.y * (BB * TT) + r0) * 192;
    #pragma unroll
    for (int mt = 0; mt < 2; ++mt) {
        #pragma unroll
        for (int nt = 0; nt < 3; ++nt) {
            int g = ng * 48 + nt * 16 + lq;
            #pragma unroll
            for (int i = 0; i < 4; ++i) {
                int row = mg * 32 + mt * 16 + quad * 4 + i;
                Pb[(size_t)row * 192 + g] = f2bf(acc[mt][nt][i]);
            }
        }
    }
}

// ---------------------------------------------------------------------------
// Kernel 1b: sum the two K-half partials; emit qws/kws [row][64] and
// vws [B][H][T] (v transposed via LDS). 256 blocks x 64 rows.
// ---------------------------------------------------------------------------
__global__ __launch_bounds__(256) void qkv_reduce(
        const unsigned short* __restrict__ Pp,
        unsigned short* __restrict__ qws, unsigned short* __restrict__ kws,
        unsigned short* __restrict__ vws) {
    __shared__ unsigned short Vt[64][72];
    int t = threadIdx.x;
    int br0 = blockIdx.x * 64;
    const size_t H2 = (size_t)BB * TT * 192;   // K-half stride
    // phase 1: q,k (cols 0..127), coalesced us8
    {
        int r = br0 + (t >> 2), cg = (t & 3) * 32;
        const unsigned short* p0 = Pp + (size_t)r * 192 + cg;
        const unsigned short* p1 = p0 + H2;
        unsigned short* dst = (cg < 64) ? (qws + (size_t)r * HH + cg)
                                        : (kws + (size_t)r * HH + (cg - 64));
        #pragma unroll
        for (int u = 0; u < 4; ++u) {
            us8 a = *(const us8*)(p0 + u * 8);
            us8 b = *(const us8*)(p1 + u * 8);
            unsigned short o[8];
            #pragma unroll
            for (int j = 0; j < 8; ++j) o[j] = f2bf(bf2f(a[j]) + bf2f(b[j]));
            *(us8*)(dst + u * 8) = *(const us8*)o;
        }
    }
    // phase 2: v (cols 128..191) -> transpose via LDS
    {
        int r = br0 + (t >> 2), ch = (t & 3) * 16;
        const unsigned short* p0 = Pp + (size_t)r * 192 + 128 + ch;
        const unsigned short* p1 = p0 + H2;
        #pragma unroll
        for (int u = 0; u < 2; ++u) {
            us8 a = *(const us8*)(p0 + u * 8);
            us8 b = *(const us8*)(p1 + u * 8);
            #pragma unroll
            for (int j = 0; j < 8; ++j)
                Vt[ch + u * 8 + j][r & 63] = f2bf(bf2f(a[j]) + bf2f(b[j]));
        }
    }
    __syncthreads();
    {
        int h = t >> 2, tb = (t & 3) * 16;
        int b = br0 >> 11, rr = br0 & (TT - 1);
        #pragma unroll
        for (int u = 0; u < 2; ++u)
            *(us8*)(vws + ((size_t)b * HH + h) * TT + rr + tb + u * 8) =
                *(const us8*)&Vt[h][tb + u * 8];
    }
}

// ---------------------------------------------------------------------------
// Kernel 2: causal attention — round-7 PASSED version, verbatim.
// ---------------------------------------------------------------------------
__global__ __launch_bounds__(128, 3) void attn(
        const unsigned short* __restrict__ qws,
        const unsigned short* __restrict__ kws,
        const unsigned short* __restrict__ vws,
        unsigned short* __restrict__ Op, float* __restrict__ Lp) {
    __shared__ unsigned short Kt[32][72];   // [key][h]
    __shared__ unsigned short Vt[64][40];   // [h][key]
    __shared__ unsigned short Ps[64][40];   // [q][key], rows wave-private
    int ti = blockIdx.x;            // 64-row q tile, 0..31
    int s  = blockIdx.y;            // kv split 0..NSPLIT-1
    int b  = blockIdx.z;
    int last = 2 * ti + 1;          // last 32-key chunk index for this tile
    if (s > last) return;
    int tid = threadIdx.x, wv = tid >> 6, lane = tid & 63;
    int half = lane >> 5, l31 = lane & 31;

    bf16x8 qf[4];
    {
        const unsigned short* qp =
            qws + ((size_t)b * TT + ti * 64 + wv * 32 + l31) * HH + half * 8;
        #pragma unroll
        for (int ks = 0; ks < 4; ++ks) qf[ks] = *(const bf16x8*)(qp + ks * 16);
    }
    f32x16 O0, O1, Lc;
    #pragma unroll
    for (int i = 0; i < 16; ++i) { O0[i] = 0.f; O1[i] = 0.f; Lc[i] = 0.f; }
    bf16x8 ones;
    #pragma unroll
    for (int i = 0; i < 8; ++i) ones[i] = (short)0x3F80;

    for (int jc = s; jc <= last; jc += NSPLIT) {
        __syncthreads();   // prior iter's K/V reads done before restage
        #pragma unroll
        for (int i = 0; i < 2; ++i) {   // K: 32 keys x 64 h
            int slot = tid + i * 128;
            int r = slot >> 3, g = slot & 7;
            *(us8*)&Kt[r][g * 8] =
                *(const us8*)(kws + ((size_t)b * TT + jc * 32 + r) * HH + g * 8);
        }
        #pragma unroll
        for (int i = 0; i < 2; ++i) {   // V: 64 h x 32 keys
            int slot = tid + i * 128;
            int h = slot >> 2, kb = slot & 3;
            *(us8*)&Vt[h][kb * 8] =
                *(const us8*)(vws + ((size_t)b * HH + h) * TT + jc * 32 + kb * 8);
        }
        __syncthreads();
        f32x16 S;
        #pragma unroll
        for (int i = 0; i < 16; ++i) S[i] = 0.f;
        #pragma unroll
        for (int ks = 0; ks < 4; ++ks) {
            bf16x8 kf = *(const bf16x8*)&Kt[l31][ks * 16 + half * 8];
            S = __builtin_amdgcn_mfma_f32_32x32x16_bf16(qf[ks], kf, S, 0, 0, 0);
        }
        bool diag = (jc >= 2 * ti + wv);   // chunk can touch this wave's diagonal
        #pragma unroll
        for (int r = 0; r < 16; ++r) {
            int pat = (r & 3) + 8 * (r >> 2) + 4 * half;    // local q row in wave
            float p = __builtin_amdgcn_exp2f(S[r]);
            if (diag && jc * 32 + l31 > ti * 64 + wv * 32 + pat) p = 0.0f;
            Ps[wv * 32 + pat][l31] = f2bf(p);
        }
        // no __syncthreads: each wave reads only its own 32 Ps rows
        #pragma unroll
        for (int ks = 0; ks < 2; ++ks) {
            bf16x8 pa  = *(const bf16x8*)&Ps[wv * 32 + l31][ks * 16 + half * 8];
            bf16x8 vf0 = *(const bf16x8*)&Vt[l31][ks * 16 + half * 8];
            bf16x8 vf1 = *(const bf16x8*)&Vt[32 + l31][ks * 16 + half * 8];
            O0 = __builtin_amdgcn_mfma_f32_32x32x16_bf16(pa, vf0, O0, 0, 0, 0);
            O1 = __builtin_amdgcn_mfma_f32_32x32x16_bf16(pa, vf1, O1, 0, 0, 0);
            Lc = __builtin_amdgcn_mfma_f32_32x32x16_bf16(pa, ones, Lc, 0, 0, 0);
        }
    }
    // deterministic per-split partial store (bf16)
    unsigned short* Ob =
        Op + (((size_t)s * BB + b) * TT + ti * 64 + wv * 32) * HH;
    #pragma unroll
    for (int r = 0; r < 16; ++r) {
        int pat = (r & 3) + 8 * (r >> 2) + 4 * half;
        Ob[(size_t)pat * HH + l31]      = f2bf(O0[r]);
        Ob[(size_t)pat * HH + 32 + l31] = f2bf(O1[r]);
    }
    if (l31 == 0) {
        #pragma unroll
        for (int r = 0; r < 16; ++r) {
            int pat = (r & 3) + 8 * (r >> 2) + 4 * half;
            Lp[((size_t)s * BB + b) * TT + ti * 64 + wv * 32 + pat] = Lc[r];
        }
    }
}

// ---------------------------------------------------------------------------
// Kernel 3: out = (sum_s Op[s]) / (sum_s Lp[s]) — round-7 PASSED version.
// 65536 threads = 256 blocks (4 threads/row).
// ---------------------------------------------------------------------------
__global__ __launch_bounds__(256) void norm_out(
        const unsigned short* __restrict__ Op, const float* __restrict__ Lp,
        float* __restrict__ out) {
    int idx = blockIdx.x * 256 + threadIdx.x;     // 65536 total
    int g = idx >> 2;                             // global row b*T + t, <16384
    int hseg = (idx & 3) * 16;
    int ti = (g & (TT - 1)) >> 6;
    int ns = min(2 * ti + 2, NSPLIT);
    float a[16];
    #pragma unroll
    for (int j = 0; j < 16; ++j) a[j] = 0.f;
    float Ls = 0.f;
    for (int s = 0; s < ns; ++s) {
        const unsigned short* base =
            Op + ((size_t)s * BB * TT + g) * HH + hseg;
        us8 u0 = *(const us8*)base;
        us8 u1 = *(const us8*)(base + 8);
        #pragma unroll
        for (int j = 0; j < 8; ++j) { a[j] += bf2f(u0[j]); a[8 + j] += bf2f(u1[j]); }
        Ls += Lp[(size_t)s * BB * TT + g];
    }
    float inv = 1.0f / Ls;
    float* ob = out + (size_t)g * HH + hseg;
    #pragma unroll
    for (int q = 0; q < 4; ++q) {
        float4 v = make_float4(a[q*4] * inv, a[q*4+1] * inv,
                               a[q*4+2] * inv, a[q*4+3] * inv);
        ((float4*)ob)[q] = v;
    }
}

// ---------------------------------------------------------------------------
extern "C" void kernel_launch(void* const* d_in, const int* in_sizes, int n_in,
                              void* d_out, int out_size, void* d_ws, size_t ws_size,
                              hipStream_t stream) {
    (void)in_sizes; (void)n_in; (void)out_size; (void)ws_size;
    const float* x  = (const float*)d_in[0];
    const float* Wq = (const float*)d_in[1];
    const float* Wk = (const float*)d_in[2];
    const float* Wv = (const float*)d_in[3];
    float* out = (float*)d_out;

    char* ws = (char*)d_ws;
    unsigned short* Wt  = (unsigned short*)ws;                          // 384 KB
    unsigned short* qws = (unsigned short*)(ws + (1u << 19));           // 2 MB
    unsigned short* kws = (unsigned short*)(ws + (1u << 19) + (1u << 21));
    unsigned short* vws = (unsigned short*)(ws + (1u << 19) + (2u << 21));
    unsigned short* Op  = (unsigned short*)(ws + (1u << 19) + (3u << 21)); // 16 MB bf16
    float*          Lp  = (float*)(ws + (1u << 19) + (3u << 21) + (1u << 24)); // 512 KB
    unsigned short* Pp  = (unsigned short*)(ws + (1u << 19) + (3u << 21)
                                            + (1u << 24) + (1u << 19));    // 12.6 MB

    prep_weights<<<48, 256, 0, stream>>>(Wq, Wk, Wv, Wt);
    proj_qkv<<<dim3(256, 2), 512, 0, stream>>>(x, Wt, Pp);
    qkv_reduce<<<256, 256, 0, stream>>>(Pp, qws, kws, vws);
    attn<<<dim3(32, NSPLIT, 8), 128, 0, stream>>>(qws, kws, vws, Op, Lp);
    norm_out<<<256, 256, 0, stream>>>(Op, Lp, out);
}